// Round 1
// baseline (420.864 us; speedup 1.0000x reference)
//
#include <hip/hip_runtime.h>
#include <cstdint>

#define NN 8192
#define DIN 512
#define DOUT 128
#define NEG_SLOPE 0.2f
#define MAXE 256
#define GEMM_BLOCKS 1024

typedef float fvec4 __attribute__((ext_vector_type(4)));

__device__ inline fvec4 ntload4(const float* p) {
    return __builtin_nontemporal_load((const fvec4*)p);
}

// ---------- K1: GEMM h = x@W + a_s/a_n epilogue ----------
// Unchanged from the measured-best R5/R8 path (8 rows/block, 1024 blocks).
// ~1.07 GFLOP fp32 vector -> ~7-10 us; finishes before K2 needs h.
__global__ __launch_bounds__(256) void k_gemm(
    const float* __restrict__ x, const float* __restrict__ W,
    const float* __restrict__ attn_self, const float* __restrict__ attn_neigh,
    float* __restrict__ h, float* __restrict__ a_s, float* __restrict__ a_n) {
    __shared__ float4 xs[1024];                  // 8 rows x 512 floats = 16 KB
    const int tid = threadIdx.x;
    const int m0 = blockIdx.x * 8;
    const float4* x4 = (const float4*)(x + (size_t)m0 * DIN);
#pragma unroll
    for (int r = 0; r < 4; ++r) xs[tid + 256 * r] = x4[tid + 256 * r];
    __syncthreads();

    const int c4 = tid & 31;
    const int rg = tid >> 5;
    const float4* W4 = (const float4*)W;         // row k = 32 float4
    const float4* xr = xs + rg * 128;
    float4 acc = {0.f, 0.f, 0.f, 0.f};
#pragma unroll 4
    for (int k4 = 0; k4 < 128; ++k4) {
        float4 xv = xr[k4];
        float4 w0 = W4[(4 * k4 + 0) * 32 + c4];
        float4 w1 = W4[(4 * k4 + 1) * 32 + c4];
        float4 w2 = W4[(4 * k4 + 2) * 32 + c4];
        float4 w3 = W4[(4 * k4 + 3) * 32 + c4];
        acc.x += xv.x * w0.x + xv.y * w1.x + xv.z * w2.x + xv.w * w3.x;
        acc.y += xv.x * w0.y + xv.y * w1.y + xv.z * w2.y + xv.w * w3.y;
        acc.z += xv.x * w0.z + xv.y * w1.z + xv.z * w2.z + xv.w * w3.z;
        acc.w += xv.x * w0.w + xv.y * w1.w + xv.z * w2.w + xv.w * w3.w;
    }
    const int row = m0 + rg;
    ((float4*)h)[(size_t)row * 32 + c4] = acc;   // normal store: keep h in L2 for K2

    float4 as4 = ((const float4*)attn_self)[c4];
    float4 an4 = ((const float4*)attn_neigh)[c4];
    float ps = acc.x * as4.x + acc.y * as4.y + acc.z * as4.z + acc.w * as4.w;
    float pn = acc.x * an4.x + acc.y * an4.y + acc.z * an4.z + acc.w * an4.w;
#pragma unroll
    for (int off = 16; off > 0; off >>= 1) {
        ps += __shfl_xor(ps, off);
        pn += __shfl_xor(pn, off);
    }
    if (c4 == 0) { a_s[row] = ps; a_n[row] = pn; }
}

// ---------- K2: fused adj-scan -> softmax -> gather, one block per row ----
// Streams the 32 KB adj row (NT, bypasses L2 so h stays resident), compacts
// edge indices to LDS, computes per-edge exp weights in LDS, then 2 threads
// per output column gather h[j] from L2 and accumulate. No e_idx round-trip,
// no separate latency-bound softmax kernel: gather latency hides under the
// adj HBM stream of co-resident blocks (8 blocks/CU, ~3.3 KB LDS).
__global__ __launch_bounds__(256) void k_row(
    const float* __restrict__ adj, const float* __restrict__ h,
    const float* __restrict__ a_s, const float* __restrict__ a_n,
    float* __restrict__ out) {
    __shared__ int s_idx[MAXE];
    __shared__ float s_w[MAXE];
    __shared__ float s_acc[DOUT];
    __shared__ float s_wp[DOUT];
    __shared__ int s_cnt;
    const int tid = threadIdx.x;
    const int i = blockIdx.x;
    if (tid == 0) s_cnt = 0;
    __syncthreads();

    // --- scan + compact (avg degree ~33, self-loop guarantees cnt >= 1) ---
    const float* arow = adj + ((size_t)i << 13);
    fvec4 v[8];
#pragma unroll
    for (int r = 0; r < 8; ++r) v[r] = ntload4(arow + 4 * (tid + 256 * r));
#pragma unroll
    for (int r = 0; r < 8; ++r) {
        int base = (tid + 256 * r) * 4;
#pragma unroll
        for (int q = 0; q < 4; ++q) {
            if (v[r][q] != 0.f) {
                int p = atomicAdd(&s_cnt, 1);
                if (p < MAXE) s_idx[p] = base + q;
            }
        }
    }
    __syncthreads();
    const int cnt = min(s_cnt, MAXE);

    // --- per-edge softmax numerators (order-invariant; |logit| small, no max
    //     pass needed: |a_s + a_n| <= ~12 << 88 = expf overflow) ---
    const float asi = a_s[i];
    if (tid < cnt) {
        int j = s_idx[tid];
        float e = asi + a_n[j];
        e = (e >= 0.f) ? e : NEG_SLOPE * e;
        s_w[tid] = __expf(e);
    }
    __syncthreads();

    // --- gather + accumulate: c = output column, two halves split edges ---
    const int c = tid & 127;
    const int half = tid >> 7;
    float acc = 0.f, wp = 0.f;
    int t = half;
    // hand-unrolled x2 for load-latency overlap (2 independent L2 gathers)
    for (; t + 2 < cnt; t += 4) {
        int j0 = s_idx[t];
        int j1 = s_idx[t + 2];
        float w0 = s_w[t];
        float w1 = s_w[t + 2];
        float h0 = h[(size_t)j0 * DOUT + c];
        float h1 = h[(size_t)j1 * DOUT + c];
        acc += w0 * h0 + w1 * h1;
        wp += w0 + w1;
    }
    for (; t < cnt; t += 2) {
        int j = s_idx[t];
        float w = s_w[t];
        acc += w * h[(size_t)j * DOUT + c];
        wp += w;
    }
    if (half == 0) { s_acc[c] = acc; s_wp[c] = wp; }
    __syncthreads();
    if (half) {
        float tot = acc + s_acc[c];
        float wsum = wp + s_wp[c];
        out[(size_t)i * DOUT + c] = fmaxf(tot * (1.0f / wsum), 0.f);
    }
}

extern "C" void kernel_launch(void* const* d_in, const int* in_sizes, int n_in,
                              void* d_out, int out_size, void* d_ws, size_t ws_size,
                              hipStream_t stream) {
    const float* x          = (const float*)d_in[0];
    const float* adj        = (const float*)d_in[1];
    const float* W          = (const float*)d_in[2];
    const float* attn_self  = (const float*)d_in[3];
    const float* attn_neigh = (const float*)d_in[4];
    float* out = (float*)d_out;

    // ws layout: h[8192*128] | a_s[8192] | a_n[8192]   (e_idx/e_cnt eliminated)
    float* h   = (float*)d_ws;
    float* a_s = h + (size_t)NN * DOUT;
    float* a_n = a_s + NN;

    hipLaunchKernelGGL(k_gemm, dim3(GEMM_BLOCKS), dim3(256), 0, stream,
                       x, W, attn_self, attn_neigh, h, a_s, a_n);
    hipLaunchKernelGGL(k_row, dim3(NN), dim3(256), 0, stream,
                       adj, h, a_s, a_n, out);
}

// Round 2
// 414.636 us; speedup vs baseline: 1.0150x; 1.0150x over previous
//
#include <hip/hip_runtime.h>
#include <cstdint>

#define NN 8192
#define DIN 512
#define DOUT 128
#define NEG_SLOPE 0.2f
#define MAXE 256
#define GEMM_BLOCKS 1024

typedef float fvec4 __attribute__((ext_vector_type(4)));

__device__ inline fvec4 ntload4(const float* p) {
    return __builtin_nontemporal_load((const fvec4*)p);
}

// ---------- Kernel 1 (fused, block-specialized; R0 measured-best) ----------
// Blocks 0..1023: GEMM h = x@W (8 rows/block) + a_s/a_n epilogue.
// Blocks 1024..9215: adj row scan -> compacted edge list in ws.
__global__ __launch_bounds__(256) void k_fused(
    const float* __restrict__ x, const float* __restrict__ W,
    const float* __restrict__ attn_self, const float* __restrict__ attn_neigh,
    const float* __restrict__ adj,
    float* __restrict__ h, float* __restrict__ a_s, float* __restrict__ a_n,
    int* __restrict__ e_cnt, int* __restrict__ e_idx) {
    __shared__ char smem_raw[16384];
    __shared__ int s_cnt;
    const int tid = threadIdx.x;
    const int bid = blockIdx.x;

    if (bid < GEMM_BLOCKS) {
        // ---- GEMM path ----
        float4* xs = (float4*)smem_raw;          // 8 rows x 512 floats = 16 KB
        const int m0 = bid * 8;
        const float4* x4 = (const float4*)(x + (size_t)m0 * DIN);
#pragma unroll
        for (int r = 0; r < 4; ++r) xs[tid + 256 * r] = x4[tid + 256 * r];
        __syncthreads();

        const int c4 = tid & 31;
        const int rg = tid >> 5;
        const float4* W4 = (const float4*)W;      // row k = 32 float4
        const float4* xr = xs + rg * 128;
        float4 acc = {0.f, 0.f, 0.f, 0.f};
#pragma unroll 4
        for (int k4 = 0; k4 < 128; ++k4) {
            float4 xv = xr[k4];
            float4 w0 = W4[(4 * k4 + 0) * 32 + c4];
            float4 w1 = W4[(4 * k4 + 1) * 32 + c4];
            float4 w2 = W4[(4 * k4 + 2) * 32 + c4];
            float4 w3 = W4[(4 * k4 + 3) * 32 + c4];
            acc.x += xv.x * w0.x + xv.y * w1.x + xv.z * w2.x + xv.w * w3.x;
            acc.y += xv.x * w0.y + xv.y * w1.y + xv.z * w2.y + xv.w * w3.y;
            acc.z += xv.x * w0.z + xv.y * w1.z + xv.z * w2.z + xv.w * w3.z;
            acc.w += xv.x * w0.w + xv.y * w1.w + xv.z * w2.w + xv.w * w3.w;
        }
        const int row = m0 + rg;
        ((float4*)h)[(size_t)row * 32 + c4] = acc;

        float4 as4 = ((const float4*)attn_self)[c4];
        float4 an4 = ((const float4*)attn_neigh)[c4];
        float ps = acc.x * as4.x + acc.y * as4.y + acc.z * as4.z + acc.w * as4.w;
        float pn = acc.x * an4.x + acc.y * an4.y + acc.z * an4.z + acc.w * an4.w;
#pragma unroll
        for (int off = 16; off > 0; off >>= 1) {
            ps += __shfl_xor(ps, off);
            pn += __shfl_xor(pn, off);
        }
        if (c4 == 0) { a_s[row] = ps; a_n[row] = pn; }
    } else {
        // ---- adj scan path: compact row i's edges into ws ----
        const int i = bid - GEMM_BLOCKS;
        int* s_idx = (int*)smem_raw;             // 1 KB alias
        if (tid == 0) s_cnt = 0;
        __syncthreads();

        const float* arow = adj + ((size_t)i << 13);
        fvec4 v[8];
#pragma unroll
        for (int r = 0; r < 8; ++r) v[r] = ntload4(arow + 4 * (tid + 256 * r));
#pragma unroll
        for (int r = 0; r < 8; ++r) {
            int base = (tid + 256 * r) * 4;
#pragma unroll
            for (int q = 0; q < 4; ++q) {
                if (v[r][q] != 0.f) {
                    int p = atomicAdd(&s_cnt, 1);
                    if (p < MAXE) s_idx[p] = base + q;
                }
            }
        }
        __syncthreads();
        const int cnt = min(s_cnt, MAXE);        // >=1 (self-loop)
        for (int t = tid; t < cnt; t += 256) e_idx[(size_t)i * MAXE + t] = s_idx[t];
        if (tid == 0) e_cnt[i] = cnt;
    }
}

// ---------- Kernel 2: wave-per-row gather, deep-MLP redesign ----------
// One 64-lane wave per row; lane owns 2 ADJACENT columns (float2). All lanes
// redundantly load the wave-uniform edge indices (int4 broadcast from e_idx)
// and redundantly compute exp weights -> zero __shfl traffic, zero final
// reduction (lsum identical across lanes, same summation order). Edges
// processed in groups of 8 with all 8 h float2-loads + 8 a_n broadcast loads
// issued before any use: ~18 loads in flight per lane vs ~4 before.
__global__ __launch_bounds__(256) void k_soft(
    const float* __restrict__ h, const float* __restrict__ a_s,
    const float* __restrict__ a_n, const int* __restrict__ e_cnt,
    const int* __restrict__ e_idx, float* __restrict__ out) {
    const int tid = threadIdx.x;
    const int lane = tid & 63;
    const int i = blockIdx.x * 4 + (tid >> 6);
    const int cnt = e_cnt[i];          // wave-uniform
    const float asi = a_s[i];
    const int rowbase = i * MAXE;      // 1 KB-aligned; int4 loads stay aligned
    const float2* h2 = (const float2*)h;

    float accx = 0.f, accy = 0.f, lsum = 0.f;
    int t = 0;
    for (; t + 8 <= cnt; t += 8) {
        const int4 ja = *(const int4*)&e_idx[rowbase + t];
        const int4 jb = *(const int4*)&e_idx[rowbase + t + 4];
        const int jj[8] = {ja.x, ja.y, ja.z, ja.w, jb.x, jb.y, jb.z, jb.w};
        float an[8];
        float2 hv[8];
#pragma unroll
        for (int u = 0; u < 8; ++u) an[u] = a_n[jj[u]];          // broadcast
#pragma unroll
        for (int u = 0; u < 8; ++u) hv[u] = h2[(size_t)jj[u] * 64 + lane];
#pragma unroll
        for (int u = 0; u < 8; ++u) {
            float e = asi + an[u];
            e = (e >= 0.f) ? e : NEG_SLOPE * e;
            float w = __expf(e);                  // |logit| small: no max pass
            lsum += w;
            accx += w * hv[u].x;
            accy += w * hv[u].y;
        }
    }
    for (; t < cnt; ++t) {                        // tail (<8 edges)
        const int j = e_idx[rowbase + t];
        float e = asi + a_n[j];
        e = (e >= 0.f) ? e : NEG_SLOPE * e;
        float w = __expf(e);
        lsum += w;
        float2 hv = h2[(size_t)j * 64 + lane];
        accx += w * hv.x;
        accy += w * hv.y;
    }
    const float inv_d = 1.0f / lsum;              // identical in every lane
    float2 o;
    o.x = fmaxf(accx * inv_d, 0.f);
    o.y = fmaxf(accy * inv_d, 0.f);
    ((float2*)out)[(size_t)i * 64 + lane] = o;
}

extern "C" void kernel_launch(void* const* d_in, const int* in_sizes, int n_in,
                              void* d_out, int out_size, void* d_ws, size_t ws_size,
                              hipStream_t stream) {
    const float* x          = (const float*)d_in[0];
    const float* adj        = (const float*)d_in[1];
    const float* W          = (const float*)d_in[2];
    const float* attn_self  = (const float*)d_in[3];
    const float* attn_neigh = (const float*)d_in[4];
    float* out = (float*)d_out;

    // ws layout: h[8192*128] | a_s[8192] | a_n[8192] | e_cnt[8192] | e_idx[8192*MAXE]
    float* h   = (float*)d_ws;
    float* a_s = h + (size_t)NN * DOUT;
    float* a_n = a_s + NN;
    int* e_cnt = (int*)(a_n + NN);
    int* e_idx = e_cnt + NN;

    hipLaunchKernelGGL(k_fused, dim3(GEMM_BLOCKS + NN), dim3(256), 0, stream,
                       x, W, attn_self, attn_neigh, adj, h, a_s, a_n, e_cnt, e_idx);
    hipLaunchKernelGGL(k_soft, dim3(NN / 4), dim3(256), 0, stream,
                       h, a_s, a_n, e_cnt, e_idx, out);
}